// Round 19
// baseline (1064.721 us; speedup 1.0000x reference)
//
#include <hip/hip_runtime.h>
#include <math.h>

#define B_ 2
#define L_ 160000
#define H_ 128
#define N_ 64
#define NL_ 4
#define LMAX_ 1024
#define TS_ 1001
#define MR_ 16
#define CLS_ 88
#define REP_ 16016

#define NSUB_ 79              // conv output sub-tiles per (b,h)
#define NJ_ 40
#define WIN_ 3208
#define WINS_ 3216            // phase-copy stride: 8 banks mod 32
#define OUTB_ 2048
#define KE_STRIDE_ 1536

typedef unsigned short ushort_t;
typedef unsigned int uint_t;
typedef short bf16x8 __attribute__((ext_vector_type(8)));
typedef float f32x4 __attribute__((ext_vector_type(4)));

__device__ __forceinline__ float bf2f(ushort_t h) {
  uint_t u = ((uint_t)h) << 16;
  return __uint_as_float(u);
}
__device__ __forceinline__ ushort_t f2bf(float f) {
  uint_t u = __float_as_uint(f);
  uint_t r = (u + 0x7fffu + ((u >> 16) & 1u)) >> 16;
  return (ushort_t)r;
}

// ---------------- encoder -> bf16 u ----------------
__global__ __launch_bounds__(256) void k_encode(const float* __restrict__ x,
                                                const float* __restrict__ enc_w,
                                                const float* __restrict__ enc_b,
                                                ushort_t* __restrict__ u) {
  int idx = blockIdx.x * 256 + threadIdx.x;    // B*H*L/8
  int idx8 = idx * 8;
  int b = idx8 / (H_ * L_);
  int rem = idx8 - b * (H_ * L_);
  int h = rem / L_;
  int l = rem - h * L_;
  float w = enc_w[h], bb = enc_b[h];
  float4 x0 = *(const float4*)(x + b * L_ + l);
  float4 x1 = *(const float4*)(x + b * L_ + l + 4);
  union { ushort_t s[8]; uint4 v; } o;
  o.s[0] = f2bf(x0.x * w + bb); o.s[1] = f2bf(x0.y * w + bb);
  o.s[2] = f2bf(x0.z * w + bb); o.s[3] = f2bf(x0.w * w + bb);
  o.s[4] = f2bf(x1.x * w + bb); o.s[5] = f2bf(x1.y * w + bb);
  o.s[6] = f2bf(x1.z * w + bb); o.s[7] = f2bf(x1.w * w + bb);
  *(uint4*)(u + (size_t)(b * H_ + h) * L_ + l) = o.v;
}

// ---------------- discretization (+ feat zero-init) ----------------
__global__ __launch_bounds__(256) void k_ct(const float* __restrict__ log_dt,
                                            const float* __restrict__ log_A_real,
                                            const float* __restrict__ A_imag,
                                            const float* __restrict__ C_re,
                                            const float* __restrict__ C_im,
                                            float* __restrict__ ct,
                                            float* __restrict__ feat) {
  int idx = blockIdx.x * 256 + threadIdx.x;
  if (idx < B_ * H_) feat[idx] = 0.f;
  if (idx >= NL_ * H_ * N_) return;
  int h = (idx / N_) % H_;
  int i = idx / (N_ * H_);
  float dt = expf(log_dt[i * H_ + h]);
  float are = -expf(log_A_real[idx]);
  float aim = A_imag[idx];
  float dr = are * dt, di = aim * dt;
  float e = expf(dr);
  float si, co;
  sincosf(di, &si, &co);
  float er = e * co - 1.0f;
  float ei = e * si;
  float den = are * are + aim * aim;
  float qr = (er * are + ei * aim) / den;
  float qi = (ei * are - er * aim) / den;
  float cr = C_re[idx], cim = C_im[idx];
  double dd = (double)aim * (double)dt * 0.15915494309189535;
  dd -= floor(dd);
  uint_t P = (uint_t)(unsigned long long)(dd * 4294967296.0);
  ct[idx * 4 + 0] = dr;
  ct[idx * 4 + 1] = __uint_as_float(P);
  ct[idx * 4 + 2] = cr * qr - cim * qi;
  ct[idx * 4 + 3] = cr * qi + cim * qr;
}

// ---------------- Ke[layer,h,s] bf16 ----------------
__global__ __launch_bounds__(256) void k_ke(const float* __restrict__ ct,
                                            ushort_t* __restrict__ Ke) {
  int q = blockIdx.x & 3;
  int ih = blockIdx.x >> 2;
  __shared__ float4 cs[N_];
  if (threadIdx.x < N_) cs[threadIdx.x] = ((const float4*)ct)[ih * N_ + threadIdx.x];
  __syncthreads();
  for (int s = q * 384 + threadIdx.x; s < (q + 1) * 384; s += 256) {
    int d = s - 256;
    float val = 0.f;
    if (d >= 0 && d < LMAX_) {
      float fl = (float)d;
      float acc = 0.f;
      #pragma unroll 4
      for (int n = 0; n < N_; n++) {
        float4 qv = cs[n];
        float e = __expf(qv.x * fl);
        uint_t ph = __float_as_uint(qv.y) * (uint_t)d;
        float ang = (float)ph * 2.3283064365386963e-10f;
        float si = __builtin_amdgcn_sinf(ang);
        float co = __builtin_amdgcn_cosf(ang);
        acc += e * (qv.z * co - qv.w * si);
      }
      val = 2.f * acc;
    }
    Ke[(size_t)ih * KE_STRIDE_ + s] = f2bf(val);
  }
}

// ---------------- W -> bf16 ----------------
__global__ __launch_bounds__(256) void k_wprep(const float* __restrict__ W,
                                               ushort_t* __restrict__ Wb) {
  int idx = blockIdx.x * 256 + threadIdx.x;
  Wb[idx] = f2bf(W[idx]);
}

// ---------------- MFMA conv + skip + GELU -> bf16 y ----------------
__global__ __launch_bounds__(256) void k_conv_mfma(const ushort_t* __restrict__ u,
                                                   const ushort_t* __restrict__ Ke,
                                                   const float* __restrict__ Dv,
                                                   ushort_t* __restrict__ y,
                                                   int layer) {
  int sub = blockIdx.x % NSUB_;
  int bh = blockIdx.x / NSUB_;
  int h = bh & (H_ - 1);
  int O0 = sub * OUTB_;
  int Gmax = O0 + 2063;
  __shared__ ushort_t win[4 * WINS_];
  __shared__ ushort_t kes[KE_STRIDE_];
  int tid = threadIdx.x;
  int lane = tid & 63, w = tid >> 6;
  int m = lane & 15, g = lane >> 4;

  {
    const ushort_t* keh0 = Ke + (size_t)(layer * H_ + h) * KE_STRIDE_;
    if (tid < KE_STRIDE_ / 8)
      *(bf16x8*)(kes + 8 * tid) = *(const bf16x8*)(keh0 + 8 * tid);
  }

  const ushort_t* ubh = u + (size_t)bh * L_;
  for (int T = tid; T < WIN_ / 8; T += 256) {
    int topt = Gmax - 8 * T;
    ushort_t vb[16];
    if (topt - 15 >= 0 && topt < L_) {
      union { uint4 q[2]; ushort_t s[16]; } ld;
      ld.q[0] = *(const uint4*)(ubh + topt - 15);
      ld.q[1] = *(const uint4*)(ubh + topt - 7);
      #pragma unroll
      for (int d = 0; d < 16; d++) vb[d] = ld.s[15 - d];
    } else {
      #pragma unroll
      for (int d = 0; d < 16; d++) {
        int gl = topt - d;
        vb[d] = (gl >= 0 && gl < L_) ? ubh[gl] : (ushort_t)0;
      }
    }
    #pragma unroll
    for (int p = 0; p < 4; p++) {
      union { bf16x8 v; ushort_t s[8]; } gr;
      #pragma unroll
      for (int e = 0; e < 8; e++) gr.s[e] = vb[p + e];
      *(bf16x8*)((char*)win + p * (2 * WINS_) + 16 * T) = gr.v;
    }
  }
  __syncthreads();

  const char* wb = (const char*)win;
  const ushort_t* kf0 = kes + 16 * m + 8 * g;
  int l0A = O0 + (w << 9);
  f32x4 accA = {0.f, 0.f, 0.f, 0.f}, accB = {0.f, 0.f, 0.f, 0.f};
  int t0 = Gmax - l0A - m + 8 * g - 256;
  bf16x8 ring[8];
  #pragma unroll
  for (int s = -8; s < NJ_; s++) {
    int tS = t0 + (s << 5);
    int pS = tS & 3;
    const char* base = wb + pS * (2 * WINS_) + 2 * (tS - pS);
    union { bf16x8 v; short4 h[2]; } f;
    f.h[0] = *(const short4*)base;
    f.h[1] = *(const short4*)(base + 8);
    if (s >= 0)
      accA = __builtin_amdgcn_mfma_f32_16x16x32_bf16(f.v, ring[s & 7], accA, 0, 0, 0);
    if (s <= 31) {
      bf16x8 kn = *(const bf16x8*)(kf0 + 32 * (s + 8));
      accB = __builtin_amdgcn_mfma_f32_16x16x32_bf16(f.v, kn, accB, 0, 0, 0);
      ring[(s + 8) & 7] = kn;
    }
  }

  float Dh = Dv[layer * H_ + h];
  ushort_t* ybh = y + (size_t)bh * L_;
  #pragma unroll
  for (int tile = 0; tile < 2; tile++) {
    f32x4 acc = tile ? accB : accA;
    int l0 = l0A + tile * 256;
    int outb = l0 + 16 * m + 4 * g;
    int tu = Gmax - outb - 3;
    int pu = tu & 3;
    union { short4 s4; ushort_t us[4]; } uu;
    uu.s4 = *(const short4*)(wb + pu * (2 * WINS_) + 2 * (tu - pu));
    union { ushort_t s[4]; short4 v; } pk;
    #pragma unroll
    for (int r = 0; r < 4; r++) {
      float uval = bf2f(uu.us[3 - r]);
      float v = acc[r] + Dh * uval;
      float z2 = 1.5957691216057308f * (v + 0.044715f * v * v * v);
      pk.s[r] = f2bf(v / (1.f + __expf(-z2)));
    }
    if (outb < L_) *(short4*)(ybh + outb) = pk.v;
  }
}

// ---------------- fused MFMA GEMM + bias + GLU + residual + LN (+pool) ----------------
// 512 threads = 2 independent 64-col groups (gq) x 4 waves each: doubles
// resident waves per block to attack latency-serialization.
__global__ __launch_bounds__(512) void k_fused(const ushort_t* __restrict__ y,
                                               const ushort_t* __restrict__ Wb,
                                               const float* __restrict__ ob,
                                               ushort_t* __restrict__ u,
                                               const float* __restrict__ lng,
                                               const float* __restrict__ lnb,
                                               int last,
                                               float* __restrict__ feat) {
  __shared__ ushort_t yT[2][64 * 136];                    // 34816 B
  __shared__ float redS[2][4 * 64] __attribute__((aligned(16)));
  __shared__ float redQ[2][4 * 64] __attribute__((aligned(16)));
  __shared__ float redM[2][64] __attribute__((aligned(16)));
  __shared__ float redR[2][64] __attribute__((aligned(16)));
  int lblk = blockIdx.x, b = blockIdx.y;
  int tid = threadIdx.x;
  int gq = tid >> 8;                  // column group 0/1
  int t = tid & 255;
  int lane = t & 63, w = t >> 6;
  int m = lane & 15, g = lane >> 4;
  int s = t & 7, kkb = t >> 3;
  int lc0 = lblk * 128 + gq * 64;

  // ---- W fragments + params (per group; L2-hot) ----
  bf16x8 Wf[4][4];
  #pragma unroll
  for (int pj = 0; pj < 4; pj++) {
    int pbase = (pj < 2) ? (32 * w + 16 * pj) : (128 + 32 * w + 16 * (pj - 2));
    const ushort_t* wrow = Wb + (pbase + m) * 128 + 8 * g;
    #pragma unroll
    for (int ks = 0; ks < 4; ks++)
      Wf[pj][ks] = *(const bf16x8*)(wrow + 32 * ks);
  }
  float oba[2], obs[2], gam[2], bet[2];
  #pragma unroll
  for (int pj = 0; pj < 2; pj++) {
    int pa = 32 * w + 16 * pj + m;
    oba[pj] = ob[pa];
    obs[pj] = ob[pa + 128];
    gam[pj] = lng[pa];
    bet[pj] = lnb[pa];
  }

  // ---- residual u prefetch ----
  short4 uoh[2][4];
  #pragma unroll
  for (int pj = 0; pj < 2; pj++) {
    int pa = 32 * w + 16 * pj + m;
    const ushort_t* urow = u + (size_t)(b * H_ + pa) * L_ + lc0;
    #pragma unroll
    for (int lj = 0; lj < 4; lj++)
      uoh[pj][lj] = *(const short4*)(urow + 16 * lj + 4 * g);
  }

  // ---- stage yT (transpose + octet swizzle) ----
  {
    #pragma unroll
    for (int p = 0; p < 4; p++) {
      int kk = kkb + 32 * p;
      const ushort_t* yp = y + ((size_t)b * H_ + kk) * L_ + lc0 + 8 * s;
      uint4 vv = *(const uint4*)yp;
      const ushort_t* hp = (const ushort_t*)&vv;
      int sw = 8 * ((kk >> 3) ^ s) + (kk & 7);
      #pragma unroll
      for (int e = 0; e < 8; e++)
        yT[gq][(8 * s + e) * 136 + sw] = hp[e];
    }
  }
  __syncthreads();

  // ---- MFMA: D[l][p] ----
  f32x4 acc[4][4];
  #pragma unroll
  for (int pj = 0; pj < 4; pj++)
    #pragma unroll
    for (int lj = 0; lj < 4; lj++) acc[pj][lj] = (f32x4){0.f, 0.f, 0.f, 0.f};
  #pragma unroll
  for (int ks = 0; ks < 4; ks++) {
    bf16x8 yf[4];
    #pragma unroll
    for (int lj = 0; lj < 4; lj++) {
      int l = 16 * lj + m;
      yf[lj] = *(const bf16x8*)(yT[gq] + l * 136 + 8 * ((4 * ks + g) ^ (l >> 3)));
    }
    #pragma unroll
    for (int pj = 0; pj < 4; pj++)
      #pragma unroll
      for (int lj = 0; lj < 4; lj++)
        acc[pj][lj] = __builtin_amdgcn_mfma_f32_16x16x32_bf16(yf[lj], Wf[pj][ks],
                                                              acc[pj][lj], 0, 0, 0);
  }

  // ---- bias + GLU + residual ----
  #pragma unroll
  for (int pj = 0; pj < 2; pj++) {
    #pragma unroll
    for (int lj = 0; lj < 4; lj++) {
      #pragma unroll
      for (int r = 0; r < 4; r++) {
        float a = acc[pj][lj][r] + oba[pj];
        float sv = acc[pj + 2][lj][r] + obs[pj];
        float uor = bf2f(((const ushort_t*)&uoh[pj][lj])[r]);
        acc[pj][lj][r] = a * (1.f / (1.f + __expf(-sv))) + uor;
      }
    }
  }

  // ---- LN stats ----
  #pragma unroll
  for (int lj = 0; lj < 4; lj++) {
    #pragma unroll
    for (int r = 0; r < 4; r++) {
      float v0 = acc[0][lj][r], v1 = acc[1][lj][r];
      float sm = v0 + v1, q = v0 * v0 + v1 * v1;
      sm += __shfl_xor(sm, 1);  q += __shfl_xor(q, 1);
      sm += __shfl_xor(sm, 2);  q += __shfl_xor(q, 2);
      sm += __shfl_xor(sm, 4);  q += __shfl_xor(q, 4);
      sm += __shfl_xor(sm, 8);  q += __shfl_xor(q, 8);
      if (m == 0) {
        int l = 16 * lj + 4 * g + r;
        redS[gq][w * 64 + l] = sm;
        redQ[gq][w * 64 + l] = q;
      }
    }
  }
  __syncthreads();
  if (t < 64) {
    float sm = redS[gq][t] + redS[gq][64 + t] + redS[gq][128 + t] + redS[gq][192 + t];
    float q = redQ[gq][t] + redQ[gq][64 + t] + redQ[gq][128 + t] + redQ[gq][192 + t];
    float mean = sm * (1.f / 128.f);
    float var = q * (1.f / 128.f) - mean * mean;
    redM[gq][t] = mean;
    redR[gq][t] = rsqrtf(var + 1e-5f);
  }
  __syncthreads();

  // ---- normalize + write u (bf16) or pool ----
  float poolAcc[2] = {0.f, 0.f};
  #pragma unroll
  for (int pj = 0; pj < 2; pj++) {
    int pa = 32 * w + 16 * pj + m;
    ushort_t* urow = u + (size_t)(b * H_ + pa) * L_ + lc0;
    #pragma unroll
    for (int lj = 0; lj < 4; lj++) {
      int l0 = 16 * lj + 4 * g;
      f32x4 mn = *(const f32x4*)(redM[gq] + l0);
      f32x4 rs = *(const f32x4*)(redR[gq] + l0);
      if (!last) {
        union { ushort_t sx[4]; short4 v; } pk;
        #pragma unroll
        for (int r = 0; r < 4; r++)
          pk.sx[r] = f2bf((acc[pj][lj][r] - mn[r]) * rs[r] * gam[pj] + bet[pj]);
        *(short4*)(urow + l0) = pk.v;
      } else {
        #pragma unroll
        for (int r = 0; r < 4; r++)
          poolAcc[pj] += (acc[pj][lj][r] - mn[r]) * rs[r] * gam[pj] + bet[pj];
      }
    }
  }
  if (last) {
    #pragma unroll
    for (int pj = 0; pj < 2; pj++) {
      int pa = 32 * w + 16 * pj + m;
      float pool = poolAcc[pj];
      pool += __shfl_xor(pool, 16);
      pool += __shfl_xor(pool, 32);
      if (g == 0) atomicAdd(&feat[b * H_ + pa], pool * (1.f / L_));
    }
  }
}

// ---------------- decoder ----------------
__global__ __launch_bounds__(256) void k_dec(const float* __restrict__ feat,
                                             const float* __restrict__ dw,
                                             const float* __restrict__ db,
                                             float* __restrict__ rep) {
  int idx = blockIdx.x * 256 + threadIdx.x;
  if (idx >= B_ * REP_) return;
  int b = idx / REP_, r = idx - b * REP_;
  float s = db[r];
  #pragma unroll 8
  for (int h = 0; h < H_; h++) s = fmaf(feat[b * H_ + h], dw[h * REP_ + r], s);
  rep[idx] = s;
}

// ---------------- heads ----------------
__global__ __launch_bounds__(256) void k_head(const float* __restrict__ rep,
                                              const float* __restrict__ hw,
                                              const float* __restrict__ hb,
                                              float* __restrict__ out) {
  int idx = blockIdx.x * 256 + threadIdx.x;
  if (idx >= 4 * B_ * TS_ * CLS_) return;
  int c = idx % CLS_;
  int t = (idx / CLS_) % TS_;
  int b = (idx / (CLS_ * TS_)) % B_;
  int k = idx / (CLS_ * TS_ * B_);
  float s = hb[k * CLS_ + c];
  const float* rp = rep + ((long long)b * TS_ + t) * MR_;
  #pragma unroll
  for (int m = 0; m < MR_; m++) s = fmaf(rp[m], hw[(k * MR_ + m) * CLS_ + c], s);
  out[idx] = s;
}

extern "C" void kernel_launch(void* const* d_in, const int* in_sizes, int n_in,
                              void* d_out, int out_size, void* d_ws, size_t ws_size,
                              hipStream_t stream) {
  const float* x = (const float*)d_in[0];
  const float* enc_w = (const float*)d_in[1];
  const float* enc_b = (const float*)d_in[2];
  const float* log_dt = (const float*)d_in[3];
  const float* log_A_real = (const float*)d_in[4];
  const float* A_imag = (const float*)d_in[5];
  const float* C_re = (const float*)d_in[6];
  const float* C_im = (const float*)d_in[7];
  const float* Dv = (const float*)d_in[8];
  const float* out_w = (const float*)d_in[9];
  const float* out_b = (const float*)d_in[10];
  const float* ln_g = (const float*)d_in[11];
  const float* ln_b = (const float*)d_in[12];
  const float* dec_w = (const float*)d_in[13];
  const float* dec_b = (const float*)d_in[14];
  const float* head_w = (const float*)d_in[15];
  const float* head_b = (const float*)d_in[16];

  // Workspace (f32 slots): u 20,480,000 (bf16) | y 20,480,000 (bf16) |
  //   Ke 393,216 | ct 131,072 | Wb 65,536 | feat 256 | rep 32,032  = 166.3 MB
  if (ws_size < 167000000ULL) return;

  float* ws = (float*)d_ws;
  ushort_t* u = (ushort_t*)ws;
  ushort_t* y = (ushort_t*)(ws + 20480000);
  ushort_t* Ke = (ushort_t*)(ws + 20480000 + 20480000);
  float* ct = ws + 20480000 + 20480000 + 393216;
  ushort_t* Wb = (ushort_t*)(ct + 131072);
  float* feat = ct + 131072 + 65536;
  float* rep = feat + 256;

  k_encode<<<(B_ * H_ * L_ / 8 + 255) / 256, 256, 0, stream>>>(x, enc_w, enc_b, u);
  k_ct<<<(NL_ * H_ * N_ + 255) / 256, 256, 0, stream>>>(log_dt, log_A_real, A_imag,
                                                        C_re, C_im, ct, feat);
  k_ke<<<NL_ * H_ * 4, 256, 0, stream>>>(ct, Ke);
  k_wprep<<<NL_ * 256 * 128 / 256, 256, 0, stream>>>(out_w, Wb);

  for (int i = 0; i < NL_; i++) {
    k_conv_mfma<<<B_ * H_ * NSUB_, 256, 0, stream>>>(u, Ke, Dv, y, i);
    k_fused<<<dim3(L_ / 128, B_), 512, 0, stream>>>(
        y, Wb + (size_t)i * 256 * 128, out_b + i * 256, u,
        ln_g + i * H_, ln_b + i * H_, (i == NL_ - 1) ? 1 : 0, feat);
  }
  k_dec<<<(B_ * REP_ + 255) / 256, 256, 0, stream>>>(feat, dec_w, dec_b, rep);
  k_head<<<(4 * B_ * TS_ * CLS_ + 255) / 256, 256, 0, stream>>>(rep, head_w, head_b,
                                                               (float*)d_out);
}

// Round 20
// 923.112 us; speedup vs baseline: 1.1534x; 1.1534x over previous
//
#include <hip/hip_runtime.h>
#include <math.h>

#define B_ 2
#define L_ 160000
#define H_ 128
#define N_ 64
#define NL_ 4
#define LMAX_ 1024
#define TS_ 1001
#define MR_ 16
#define CLS_ 88
#define REP_ 16016

#define NSUB_ 79              // conv output sub-tiles per (b,h); grid = 20224 = 8*2528
#define CPX_ 2528             // blocks per XCD for the conv swizzle
#define NJ_ 40
#define WIN_ 3208
#define WINS_ 3216            // phase-copy stride: 8 banks mod 32
#define OUTB_ 2048
#define KE_STRIDE_ 1536

typedef unsigned short ushort_t;
typedef unsigned int uint_t;
typedef short bf16x8 __attribute__((ext_vector_type(8)));
typedef float f32x4 __attribute__((ext_vector_type(4)));

__device__ __forceinline__ float bf2f(ushort_t h) {
  uint_t u = ((uint_t)h) << 16;
  return __uint_as_float(u);
}
__device__ __forceinline__ ushort_t f2bf(float f) {
  uint_t u = __float_as_uint(f);
  uint_t r = (u + 0x7fffu + ((u >> 16) & 1u)) >> 16;
  return (ushort_t)r;
}

// ---------------- encoder -> bf16 u ----------------
__global__ __launch_bounds__(256) void k_encode(const float* __restrict__ x,
                                                const float* __restrict__ enc_w,
                                                const float* __restrict__ enc_b,
                                                ushort_t* __restrict__ u) {
  int idx = blockIdx.x * 256 + threadIdx.x;    // B*H*L/8
  int idx8 = idx * 8;
  int b = idx8 / (H_ * L_);
  int rem = idx8 - b * (H_ * L_);
  int h = rem / L_;
  int l = rem - h * L_;
  float w = enc_w[h], bb = enc_b[h];
  float4 x0 = *(const float4*)(x + b * L_ + l);
  float4 x1 = *(const float4*)(x + b * L_ + l + 4);
  union { ushort_t s[8]; uint4 v; } o;
  o.s[0] = f2bf(x0.x * w + bb); o.s[1] = f2bf(x0.y * w + bb);
  o.s[2] = f2bf(x0.z * w + bb); o.s[3] = f2bf(x0.w * w + bb);
  o.s[4] = f2bf(x1.x * w + bb); o.s[5] = f2bf(x1.y * w + bb);
  o.s[6] = f2bf(x1.z * w + bb); o.s[7] = f2bf(x1.w * w + bb);
  *(uint4*)(u + (size_t)(b * H_ + h) * L_ + l) = o.v;
}

// ---------------- discretization (+ feat zero-init) ----------------
__global__ __launch_bounds__(256) void k_ct(const float* __restrict__ log_dt,
                                            const float* __restrict__ log_A_real,
                                            const float* __restrict__ A_imag,
                                            const float* __restrict__ C_re,
                                            const float* __restrict__ C_im,
                                            float* __restrict__ ct,
                                            float* __restrict__ feat) {
  int idx = blockIdx.x * 256 + threadIdx.x;
  if (idx < B_ * H_) feat[idx] = 0.f;
  if (idx >= NL_ * H_ * N_) return;
  int h = (idx / N_) % H_;
  int i = idx / (N_ * H_);
  float dt = expf(log_dt[i * H_ + h]);
  float are = -expf(log_A_real[idx]);
  float aim = A_imag[idx];
  float dr = are * dt, di = aim * dt;
  float e = expf(dr);
  float si, co;
  sincosf(di, &si, &co);
  float er = e * co - 1.0f;
  float ei = e * si;
  float den = are * are + aim * aim;
  float qr = (er * are + ei * aim) / den;
  float qi = (ei * are - er * aim) / den;
  float cr = C_re[idx], cim = C_im[idx];
  double dd = (double)aim * (double)dt * 0.15915494309189535;
  dd -= floor(dd);
  uint_t P = (uint_t)(unsigned long long)(dd * 4294967296.0);
  ct[idx * 4 + 0] = dr;
  ct[idx * 4 + 1] = __uint_as_float(P);
  ct[idx * 4 + 2] = cr * qr - cim * qi;
  ct[idx * 4 + 3] = cr * qi + cim * qr;
}

// ---------------- Ke[layer,h,s] bf16 ----------------
__global__ __launch_bounds__(256) void k_ke(const float* __restrict__ ct,
                                            ushort_t* __restrict__ Ke) {
  int q = blockIdx.x & 3;
  int ih = blockIdx.x >> 2;
  __shared__ float4 cs[N_];
  if (threadIdx.x < N_) cs[threadIdx.x] = ((const float4*)ct)[ih * N_ + threadIdx.x];
  __syncthreads();
  for (int s = q * 384 + threadIdx.x; s < (q + 1) * 384; s += 256) {
    int d = s - 256;
    float val = 0.f;
    if (d >= 0 && d < LMAX_) {
      float fl = (float)d;
      float acc = 0.f;
      #pragma unroll 4
      for (int n = 0; n < N_; n++) {
        float4 qv = cs[n];
        float e = __expf(qv.x * fl);
        uint_t ph = __float_as_uint(qv.y) * (uint_t)d;
        float ang = (float)ph * 2.3283064365386963e-10f;
        float si = __builtin_amdgcn_sinf(ang);
        float co = __builtin_amdgcn_cosf(ang);
        acc += e * (qv.z * co - qv.w * si);
      }
      val = 2.f * acc;
    }
    Ke[(size_t)ih * KE_STRIDE_ + s] = f2bf(val);
  }
}

// ---------------- W -> bf16 ----------------
__global__ __launch_bounds__(256) void k_wprep(const float* __restrict__ W,
                                               ushort_t* __restrict__ Wb) {
  int idx = blockIdx.x * 256 + threadIdx.x;
  Wb[idx] = f2bf(W[idx]);
}

// ---------------- MFMA conv + skip + GELU -> bf16 y (XCD-swizzled grid) ----------------
// Swizzle: works with the same (b,h) stay on ONE XCD so the 1024-col halo
// shared by adjacent sub-tiles hits that XCD's L2 instead of re-fetching.
__global__ __launch_bounds__(256) void k_conv_mfma(const ushort_t* __restrict__ u,
                                                   const ushort_t* __restrict__ Ke,
                                                   const float* __restrict__ Dv,
                                                   ushort_t* __restrict__ y,
                                                   int layer) {
  int bid = blockIdx.x;                        // 20224 = 8 * CPX_
  int work = (bid & 7) * CPX_ + (bid >> 3);    // bijective XCD swizzle (T1)
  int sub = work % NSUB_;
  int bh = work / NSUB_;
  int h = bh & (H_ - 1);
  int O0 = sub * OUTB_;
  int Gmax = O0 + 2063;
  __shared__ ushort_t win[4 * WINS_];
  __shared__ ushort_t kes[KE_STRIDE_];
  int tid = threadIdx.x;
  int lane = tid & 63, w = tid >> 6;
  int m = lane & 15, g = lane >> 4;

  {
    const ushort_t* keh0 = Ke + (size_t)(layer * H_ + h) * KE_STRIDE_;
    if (tid < KE_STRIDE_ / 8)
      *(bf16x8*)(kes + 8 * tid) = *(const bf16x8*)(keh0 + 8 * tid);
  }

  const ushort_t* ubh = u + (size_t)bh * L_;
  for (int T = tid; T < WIN_ / 8; T += 256) {
    int topt = Gmax - 8 * T;
    ushort_t vb[16];
    if (topt - 15 >= 0 && topt < L_) {
      union { uint4 q[2]; ushort_t s[16]; } ld;
      ld.q[0] = *(const uint4*)(ubh + topt - 15);
      ld.q[1] = *(const uint4*)(ubh + topt - 7);
      #pragma unroll
      for (int d = 0; d < 16; d++) vb[d] = ld.s[15 - d];
    } else {
      #pragma unroll
      for (int d = 0; d < 16; d++) {
        int gl = topt - d;
        vb[d] = (gl >= 0 && gl < L_) ? ubh[gl] : (ushort_t)0;
      }
    }
    #pragma unroll
    for (int p = 0; p < 4; p++) {
      union { bf16x8 v; ushort_t s[8]; } gr;
      #pragma unroll
      for (int e = 0; e < 8; e++) gr.s[e] = vb[p + e];
      *(bf16x8*)((char*)win + p * (2 * WINS_) + 16 * T) = gr.v;
    }
  }
  __syncthreads();

  const char* wb = (const char*)win;
  const ushort_t* kf0 = kes + 16 * m + 8 * g;
  int l0A = O0 + (w << 9);
  f32x4 accA = {0.f, 0.f, 0.f, 0.f}, accB = {0.f, 0.f, 0.f, 0.f};
  int t0 = Gmax - l0A - m + 8 * g - 256;
  bf16x8 ring[8];
  #pragma unroll
  for (int s = -8; s < NJ_; s++) {
    int tS = t0 + (s << 5);
    int pS = tS & 3;
    const char* base = wb + pS * (2 * WINS_) + 2 * (tS - pS);
    union { bf16x8 v; short4 h[2]; } f;
    f.h[0] = *(const short4*)base;
    f.h[1] = *(const short4*)(base + 8);
    if (s >= 0)
      accA = __builtin_amdgcn_mfma_f32_16x16x32_bf16(f.v, ring[s & 7], accA, 0, 0, 0);
    if (s <= 31) {
      bf16x8 kn = *(const bf16x8*)(kf0 + 32 * (s + 8));
      accB = __builtin_amdgcn_mfma_f32_16x16x32_bf16(f.v, kn, accB, 0, 0, 0);
      ring[(s + 8) & 7] = kn;
    }
  }

  float Dh = Dv[layer * H_ + h];
  ushort_t* ybh = y + (size_t)bh * L_;
  #pragma unroll
  for (int tile = 0; tile < 2; tile++) {
    f32x4 acc = tile ? accB : accA;
    int l0 = l0A + tile * 256;
    int outb = l0 + 16 * m + 4 * g;
    int tu = Gmax - outb - 3;
    int pu = tu & 3;
    union { short4 s4; ushort_t us[4]; } uu;
    uu.s4 = *(const short4*)(wb + pu * (2 * WINS_) + 2 * (tu - pu));
    union { ushort_t s[4]; short4 v; } pk;
    #pragma unroll
    for (int r = 0; r < 4; r++) {
      float uval = bf2f(uu.us[3 - r]);
      float v = acc[r] + Dh * uval;
      float z2 = 1.5957691216057308f * (v + 0.044715f * v * v * v);
      pk.s[r] = f2bf(v / (1.f + __expf(-z2)));
    }
    if (outb < L_) *(short4*)(ybh + outb) = pk.v;
  }
}

// ---------------- fused MFMA GEMM + bias + GLU + residual + LN (+pool on last) ----------------
// Round-14 structure (best measured): all global loads issued before stage+barrier.
__global__ __launch_bounds__(256) void k_fused(const ushort_t* __restrict__ y,
                                               const ushort_t* __restrict__ Wb,
                                               const float* __restrict__ ob,
                                               ushort_t* __restrict__ u,
                                               const float* __restrict__ lng,
                                               const float* __restrict__ lnb,
                                               int last,
                                               float* __restrict__ feat) {
  __shared__ ushort_t yT[64 * 136];                       // 17408 B
  __shared__ float redS[4 * 64] __attribute__((aligned(16)));
  __shared__ float redQ[4 * 64] __attribute__((aligned(16)));
  __shared__ float redM[64] __attribute__((aligned(16)));
  __shared__ float redR[64] __attribute__((aligned(16)));
  int lblk = blockIdx.x, b = blockIdx.y;
  int lc0 = lblk * 64;
  int tid = threadIdx.x;
  int lane = tid & 63, w = tid >> 6;
  int m = lane & 15, g = lane >> 4;

  // ---- 1. W fragments: all 16 issued up front ----
  bf16x8 Wf[4][4];   // [pj][ks]
  #pragma unroll
  for (int pj = 0; pj < 4; pj++) {
    int pbase = (pj < 2) ? (32 * w + 16 * pj) : (128 + 32 * w + 16 * (pj - 2));
    const ushort_t* wrow = Wb + (pbase + m) * 128 + 8 * g;
    #pragma unroll
    for (int ks = 0; ks < 4; ks++)
      Wf[pj][ks] = *(const bf16x8*)(wrow + 32 * ks);
  }

  // ---- 2. residual u prefetch (bf16) + params ----
  short4 uoh[2][4];
  float oba[2], obs[2], gam[2], bet[2];
  #pragma unroll
  for (int pj = 0; pj < 2; pj++) {
    int pa = 32 * w + 16 * pj + m;
    const ushort_t* urow = u + (size_t)(b * H_ + pa) * L_ + lc0;
    #pragma unroll
    for (int lj = 0; lj < 4; lj++)
      uoh[pj][lj] = *(const short4*)(urow + 16 * lj + 4 * g);
    oba[pj] = ob[pa];
    obs[pj] = ob[pa + 128];
    gam[pj] = lng[pa];
    bet[pj] = lnb[pa];
  }

  // ---- 3. stage yT (transpose + octet swizzle) ----
  {
    int s = tid & 7;
    int kkb = tid >> 3;
    #pragma unroll
    for (int p = 0; p < 4; p++) {
      int kk = kkb + 32 * p;
      const ushort_t* yp = y + ((size_t)b * H_ + kk) * L_ + lc0 + 8 * s;
      uint4 vv = *(const uint4*)yp;
      const ushort_t* hp = (const ushort_t*)&vv;
      int sw = 8 * ((kk >> 3) ^ s) + (kk & 7);
      #pragma unroll
      for (int e = 0; e < 8; e++)
        yT[(8 * s + e) * 136 + sw] = hp[e];
    }
  }
  __syncthreads();

  // ---- 4. MFMA: D[l][p], acc[pj][lj]; pj 0,1 = a-half, 2,3 = s-half ----
  f32x4 acc[4][4];
  #pragma unroll
  for (int pj = 0; pj < 4; pj++)
    #pragma unroll
    for (int lj = 0; lj < 4; lj++) acc[pj][lj] = (f32x4){0.f, 0.f, 0.f, 0.f};
  #pragma unroll
  for (int ks = 0; ks < 4; ks++) {
    bf16x8 yf[4];
    #pragma unroll
    for (int lj = 0; lj < 4; lj++) {
      int l = 16 * lj + m;
      yf[lj] = *(const bf16x8*)(yT + l * 136 + 8 * ((4 * ks + g) ^ (l >> 3)));
    }
    #pragma unroll
    for (int pj = 0; pj < 4; pj++)
      #pragma unroll
      for (int lj = 0; lj < 4; lj++)
        acc[pj][lj] = __builtin_amdgcn_mfma_f32_16x16x32_bf16(yf[lj], Wf[pj][ks],
                                                              acc[pj][lj], 0, 0, 0);
  }

  // ---- 5. bias + GLU + residual (register-resident bf16 uo) ----
  #pragma unroll
  for (int pj = 0; pj < 2; pj++) {
    #pragma unroll
    for (int lj = 0; lj < 4; lj++) {
      #pragma unroll
      for (int r = 0; r < 4; r++) {
        float a = acc[pj][lj][r] + oba[pj];
        float sv = acc[pj + 2][lj][r] + obs[pj];
        float uor = bf2f(((const ushort_t*)&uoh[pj][lj])[r]);
        acc[pj][lj][r] = a * (1.f / (1.f + __expf(-sv))) + uor;
      }
    }
  }

  // ---- 6. LN stats: shfl over m -> cross-wave LDS ----
  #pragma unroll
  for (int lj = 0; lj < 4; lj++) {
    #pragma unroll
    for (int r = 0; r < 4; r++) {
      float v0 = acc[0][lj][r], v1 = acc[1][lj][r];
      float s = v0 + v1, q = v0 * v0 + v1 * v1;
      s += __shfl_xor(s, 1);  q += __shfl_xor(q, 1);
      s += __shfl_xor(s, 2);  q += __shfl_xor(q, 2);
      s += __shfl_xor(s, 4);  q += __shfl_xor(q, 4);
      s += __shfl_xor(s, 8);  q += __shfl_xor(q, 8);
      if (m == 0) {
        int l = 16 * lj + 4 * g + r;
        redS[w * 64 + l] = s;
        redQ[w * 64 + l] = q;
      }
    }
  }
  __syncthreads();
  if (tid < 64) {
    float s = redS[tid] + redS[64 + tid] + redS[128 + tid] + redS[192 + tid];
    float q = redQ[tid] + redQ[64 + tid] + redQ[128 + tid] + redQ[192 + tid];
    float mean = s * (1.f / 128.f);
    float var = q * (1.f / 128.f) - mean * mean;
    redM[tid] = mean;
    redR[tid] = rsqrtf(var + 1e-5f);
  }
  __syncthreads();

  // ---- 7. normalize + write u (bf16 short4) or pool into feat ----
  #pragma unroll
  for (int pj = 0; pj < 2; pj++) {
    int pa = 32 * w + 16 * pj + m;
    ushort_t* urow = u + (size_t)(b * H_ + pa) * L_ + lc0;
    float pool = 0.f;
    #pragma unroll
    for (int lj = 0; lj < 4; lj++) {
      int l0 = 16 * lj + 4 * g;
      f32x4 mn = *(const f32x4*)(redM + l0);
      f32x4 rs = *(const f32x4*)(redR + l0);
      if (!last) {
        union { ushort_t sx[4]; short4 v; } pk;
        #pragma unroll
        for (int r = 0; r < 4; r++)
          pk.sx[r] = f2bf((acc[pj][lj][r] - mn[r]) * rs[r] * gam[pj] + bet[pj]);
        *(short4*)(urow + l0) = pk.v;
      } else {
        #pragma unroll
        for (int r = 0; r < 4; r++)
          pool += (acc[pj][lj][r] - mn[r]) * rs[r] * gam[pj] + bet[pj];
      }
    }
    if (last) {
      pool += __shfl_xor(pool, 16);
      pool += __shfl_xor(pool, 32);
      if (g == 0) atomicAdd(&feat[b * H_ + pa], pool * (1.f / L_));
    }
  }
}

// ---------------- decoder ----------------
__global__ __launch_bounds__(256) void k_dec(const float* __restrict__ feat,
                                             const float* __restrict__ dw,
                                             const float* __restrict__ db,
                                             float* __restrict__ rep) {
  int idx = blockIdx.x * 256 + threadIdx.x;
  if (idx >= B_ * REP_) return;
  int b = idx / REP_, r = idx - b * REP_;
  float s = db[r];
  #pragma unroll 8
  for (int h = 0; h < H_; h++) s = fmaf(feat[b * H_ + h], dw[h * REP_ + r], s);
  rep[idx] = s;
}

// ---------------- heads ----------------
__global__ __launch_bounds__(256) void k_head(const float* __restrict__ rep,
                                              const float* __restrict__ hw,
                                              const float* __restrict__ hb,
                                              float* __restrict__ out) {
  int idx = blockIdx.x * 256 + threadIdx.x;
  if (idx >= 4 * B_ * TS_ * CLS_) return;
  int c = idx % CLS_;
  int t = (idx / CLS_) % TS_;
  int b = (idx / (CLS_ * TS_)) % B_;
  int k = idx / (CLS_ * TS_ * B_);
  float s = hb[k * CLS_ + c];
  const float* rp = rep + ((long long)b * TS_ + t) * MR_;
  #pragma unroll
  for (int m = 0; m < MR_; m++) s = fmaf(rp[m], hw[(k * MR_ + m) * CLS_ + c], s);
  out[idx] = s;
}

extern "C" void kernel_launch(void* const* d_in, const int* in_sizes, int n_in,
                              void* d_out, int out_size, void* d_ws, size_t ws_size,
                              hipStream_t stream) {
  const float* x = (const float*)d_in[0];
  const float* enc_w = (const float*)d_in[1];
  const float* enc_b = (const float*)d_in[2];
  const float* log_dt = (const float*)d_in[3];
  const float* log_A_real = (const float*)d_in[4];
  const float* A_imag = (const float*)d_in[5];
  const float* C_re = (const float*)d_in[6];
  const float* C_im = (const float*)d_in[7];
  const float* Dv = (const float*)d_in[8];
  const float* out_w = (const float*)d_in[9];
  const float* out_b = (const float*)d_in[10];
  const float* ln_g = (const float*)d_in[11];
  const float* ln_b = (const float*)d_in[12];
  const float* dec_w = (const float*)d_in[13];
  const float* dec_b = (const float*)d_in[14];
  const float* head_w = (const float*)d_in[15];
  const float* head_b = (const float*)d_in[16];

  // Workspace (f32 slots): u 20,480,000 (bf16) | y 20,480,000 (bf16) |
  //   Ke 393,216 | ct 131,072 | Wb 65,536 | feat 256 | rep 32,032  = 166.3 MB
  if (ws_size < 167000000ULL) return;

  float* ws = (float*)d_ws;
  ushort_t* u = (ushort_t*)ws;
  ushort_t* y = (ushort_t*)(ws + 20480000);
  ushort_t* Ke = (ushort_t*)(ws + 20480000 + 20480000);
  float* ct = ws + 20480000 + 20480000 + 393216;
  ushort_t* Wb = (ushort_t*)(ct + 131072);
  float* feat = ct + 131072 + 65536;
  float* rep = feat + 256;

  k_encode<<<(B_ * H_ * L_ / 8 + 255) / 256, 256, 0, stream>>>(x, enc_w, enc_b, u);
  k_ct<<<(NL_ * H_ * N_ + 255) / 256, 256, 0, stream>>>(log_dt, log_A_real, A_imag,
                                                        C_re, C_im, ct, feat);
  k_ke<<<NL_ * H_ * 4, 256, 0, stream>>>(ct, Ke);
  k_wprep<<<NL_ * 256 * 128 / 256, 256, 0, stream>>>(out_w, Wb);

  for (int i = 0; i < NL_; i++) {
    k_conv_mfma<<<B_ * H_ * NSUB_, 256, 0, stream>>>(u, Ke, Dv, y, i);
    k_fused<<<dim3(L_ / 64, B_), 256, 0, stream>>>(
        y, Wb + (size_t)i * 256 * 128, out_b + i * 256, u,
        ln_g + i * H_, ln_b + i * H_, (i == NL_ - 1) ? 1 : 0, feat);
  }
  k_dec<<<(B_ * REP_ + 255) / 256, 256, 0, stream>>>(feat, dec_w, dec_b, rep);
  k_head<<<(4 * B_ * TS_ * CLS_ + 255) / 256, 256, 0, stream>>>(rep, head_w, head_b,
                                                               (float*)d_out);
}